// Round 10
// baseline (483.076 us; speedup 1.0000x reference)
//
#include <hip/hip_runtime.h>
#include <stdint.h>

// Problem constants (fixed by the reference's config)
#define HH 480
#define WW 640
#define NN (HH * WW)
#define BB 8
#define PP 4
#define EPS 1e-9f

// Output-tile geometry: block owns a TW x TH OUTPUT tile. 640/64=10, 480/32=15.
#define TW 64
#define TH 32
#define HALO 12
#define RGW (TW + 2 * HALO)   // 88
#define RGH (TH + 2 * HALO)   // 56
#define RGN (RGW * RGH)       // 4928
#define NBX (WW / TW)         // 10
#define NBY (HH / TH)         // 15

// Binning: sources bucketed by floor cell.
#define BINSX (TW + 1)        // 65
#define BINSY (TH + 1)        // 33
#define NBINS (BINSX * BINSY) // 2145
#define CAP 4                 // slots/bin; overflow -> list path

// guaranteed-in-image source id (rel HALO,HALO) for dead predicated loads
#define SAFE_ID ((HALO << 7) | HALO)

// far/overflow contribution list: entries (fi, w, w*fy, w*fx). Measured
// far+overflow ~50K entries on this input; 512K cap = 10x headroom.
#define LCAP (512u * 1024u)

__device__ __forceinline__ void gatomic(float* p, float v) {
    unsafeAtomicAdd(p, v);    // native global_atomic_add_f32, rare path only
}

// Phase A: scan halo region, bin sources by floor cell (1 LDS rtn-atomic per
// source); far/overflow contributions appended to a global list exactly once.
// Phase B: per output cell, 4 bins x 4 slots: ISSUE phase loads all 16 flow
// pairs into registers (pipelined), EVAL phase is pure VALU with expressions
// bit-identical to phase A / the reference. Epilogue writes S planes AND the
// normalized output directly (fixup kernels correct list-touched pixels).
__global__ __launch_bounds__(256, 4)
void bin_gather_splat(const float* __restrict__ fx_all,
                      const float* __restrict__ fy_all,
                      const int* __restrict__ i_ptr,
                      const int* __restrict__ tref_ptr,
                      float* __restrict__ Sw, float* __restrict__ Swy, float* __restrict__ Swx,
                      unsigned* __restrict__ lcount, int4* __restrict__ llist,
                      float* __restrict__ out) {
    __shared__ unsigned cnt[NBINS];   // 8580 B
    __shared__ ushort4  ids4[NBINS];  // 17160 B
    const int tid = threadIdx.x;
    for (int e = tid; e < NBINS; e += 256) cnt[e] = 0;
    __syncthreads();

    const int bx = blockIdx.x, by = blockIdx.y, b = blockIdx.z;
    const int tx0 = bx * TW, ty0 = by * TH;
    const int i = *i_ptr;
    const float dt = (float)(*tref_ptr - i);
    const float* __restrict__ fxp = fx_all + (size_t)(b * PP + i) * NN;
    const float* __restrict__ fyp = fy_all + (size_t)(b * PP + i) * NN;
    const size_t BN = (size_t)BB * NN;

    // ---------------- phase A ----------------
    for (int sp = tid; sp < RGN; sp += 256) {
        int sy = sp / RGW, sx = sp - sy * RGW;
        int gy = ty0 - HALO + sy, gx = tx0 - HALO + sx;
        if ((unsigned)gy >= (unsigned)HH || (unsigned)gx >= (unsigned)WW) continue;
        int p = gy * WW + gx;
        float fy = fyp[p], fx = fxp[p];
        float wyf = (float)gy + dt * fy;
        float wxf = (float)gx + dt * fx;
        // purge_unfeasible
        if (!(wyf >= 0.0f && wyf <= (float)(HH - 1) &&
              wxf >= 0.0f && wxf <= (float)(WW - 1))) continue;
        float tyf = floorf(wyf), lxf = floorf(wxf);
        int iy0 = (int)tyf, ix0 = (int)lxf;   // >= 0 (inside test)
        int br = iy0 - ty0, bc = ix0 - tx0;

        bool overflow = false;
        if (br >= -1 && br < TH && bc >= -1 && bc < TW) {
            int bin = (br + 1) * BINSX + (bc + 1);
            unsigned slot = atomicAdd(&cnt[bin], 1u);   // native ds_add_rtn_u32
            if (slot < CAP)
                ((unsigned short*)&ids4[bin])[slot] = (unsigned short)((sy << 7) | sx);
            else overflow = true;
        }
        bool interior = ((unsigned)(gx - tx0) < (unsigned)TW) &&
                        ((unsigned)(gy - ty0) < (unsigned)TH);
        if (overflow || interior) {
            float fry = wyf - tyf, frx = wxf - lxf;
            float wts[4] = {(1.0f - fry) * (1.0f - frx),
                            (1.0f - fry) * frx,
                            fry * (1.0f - frx),
                            fry * frx};
#pragma unroll
            for (int k = 0; k < 4; ++k) {
                int iy = iy0 + (k >> 1), ix = ix0 + (k & 1);
                if ((unsigned)iy >= (unsigned)HH || (unsigned)ix >= (unsigned)WW) continue;
                bool inT = ((unsigned)(iy - ty0) < (unsigned)TH) &&
                           ((unsigned)(ix - tx0) < (unsigned)TW);
                // far: s's owner must emit (tile(N) never scans s)
                int tnx = (ix >> 6) << 6;   // tile(N) origin, TW=64
                int tny = (iy >> 5) << 5;   // TH=32
                int ddx = gx < tnx ? tnx - gx : (gx > tnx + (TW - 1) ? gx - tnx - (TW - 1) : 0);
                int ddy = gy < tny ? tny - gy : (gy > tny + (TH - 1) ? gy - tny - (TH - 1) : 0);
                bool far = (ddx > HALO) || (ddy > HALO);
                if ((interior && far) || (overflow && inT)) {
                    int fi = b * NN + iy * WW + ix;
                    float w = wts[k];
                    unsigned slot = atomicAdd(lcount, 1u);
                    if (slot < LCAP)
                        llist[slot] = make_int4(fi, __float_as_int(w),
                                                __float_as_int(w * fy),
                                                __float_as_int(w * fx));
                }
            }
        }
    }
    __syncthreads();

    // ---------------- phase B: issue-then-eval pipelined gather ----------------
    for (int e = tid; e < TW * TH; e += 256) {
        int r = e >> 6, c = e & 63;           // TW=64
        float cy = (float)(ty0 + r), cx = (float)(tx0 + c);

        int   id16[16];
        float fyv[16], fxv[16];
        // ISSUE: all 16 slot loads independent -> compiler can keep them in flight
#pragma unroll
        for (int u = 0; u < 4; ++u) {
            int dr = u >> 1, dc = u & 1;
            int bin = (r + dr) * BINSX + (c + dc);
            unsigned n = cnt[bin];
            if (n > CAP) n = CAP;
            ushort4 s4 = ids4[bin];           // one ds_read_b64
            unsigned short sl[4] = {s4.x, s4.y, s4.z, s4.w};
#pragma unroll
            for (int t = 0; t < CAP; ++t) {
                int idx = u * 4 + t;
                bool valid = (unsigned)t < n;
                int sid = valid ? (int)sl[t] : SAFE_ID;
                id16[idx] = valid ? (int)sl[t] : -1;
                int sy = sid >> 7, sx = sid & 127;
                int p = (ty0 - HALO + sy) * WW + (tx0 - HALO + sx);  // in-image
                fyv[idx] = fyp[p];
                fxv[idx] = fxp[p];
            }
        }
        // EVAL: pure VALU, expressions identical to R9 (verified) / reference
        float ws = 0.f, wys = 0.f, wxs = 0.f;
#pragma unroll
        for (int idx = 0; idx < 16; ++idx) {
            int id = id16[idx];
            int sy = id >> 7, sx = id & 127;  // id=-1 -> garbage, weight masked to 0
            float gyf = (float)(ty0 - HALO + sy);
            float gxf = (float)(tx0 - HALO + sx);
            float fy = fyv[idx], fx = fxv[idx];
            float wyf = gyf + dt * fy;        // same expr as phase A
            float wxf = gxf + dt * fx;
            float ay = 1.0f - fabsf(wyf - cy);
            float ax = 1.0f - fabsf(wxf - cx);
            float w = fmaxf(ay, 0.f) * fmaxf(ax, 0.f);
            w = (id >= 0) ? w : 0.f;
            ws  += w;
            wys += w * fy;
            wxs += w * fx;
        }
        size_t o = (size_t)b * NN + (size_t)(ty0 + r) * WW + (tx0 + c);
        Sw[o] = ws; Swy[o] = wys; Swx[o] = wxs;
        float d = ws + EPS;
        out[o]      = wxs / d;                // provisional; fixed up if F-touched
        out[BN + o] = wys / d;
    }
}

// ---------------- fixups for list-touched pixels ----------------
__global__ __launch_bounds__(256)
void fix_add(const unsigned* __restrict__ lcount, const int4* __restrict__ llist,
             float* __restrict__ Sw, float* __restrict__ Swy, float* __restrict__ Swx) {
    unsigned n = *lcount; if (n > LCAP) n = LCAP;
    unsigned e = blockIdx.x * blockDim.x + threadIdx.x;
    if (e >= n) return;
    int4 v = llist[e];
    gatomic(&Sw[v.x],  __int_as_float(v.y));
    gatomic(&Swy[v.x], __int_as_float(v.z));
    gatomic(&Swx[v.x], __int_as_float(v.w));
}

__global__ __launch_bounds__(256)
void fix_write(const unsigned* __restrict__ lcount, const int4* __restrict__ llist,
               const float* __restrict__ Sw, const float* __restrict__ Swy,
               const float* __restrict__ Swx, float* __restrict__ out) {
    unsigned n = *lcount; if (n > LCAP) n = LCAP;
    unsigned e = blockIdx.x * blockDim.x + threadIdx.x;
    if (e >= n) return;
    int fi = llist[e].x;                      // duplicates benign (idempotent)
    float d = Sw[fi] + EPS;
    out[fi] = Swx[fi] / d;
    out[(size_t)BB * NN + fi] = Swy[fi] / d;
}

// ---------------- fallback path (R1, needs only 29.5 MB ws) ----------------

__global__ void splat_kernel(const float* __restrict__ fx_all,
                             const float* __restrict__ fy_all,
                             const int* __restrict__ i_ptr,
                             const int* __restrict__ tref_ptr,
                             float* __restrict__ sum_w,
                             float* __restrict__ sum_wy,
                             float* __restrict__ sum_wx) {
    int t = blockIdx.x * blockDim.x + threadIdx.x;
    if (t >= BB * NN) return;
    int b = t / NN;
    int p = t - b * NN;
    int i = *i_ptr;
    float dt = (float)(*tref_ptr - i);
    const float fx = fx_all[(size_t)(b * PP + i) * NN + p];
    const float fy = fy_all[(size_t)(b * PP + i) * NN + p];
    float gy = (float)(p / WW);
    float gx = (float)(p - (p / WW) * WW);
    float wy = gy + dt * fy;
    float wx = gx + dt * fx;
    bool inside = (wy >= 0.0f) && (wy <= (float)(HH - 1)) &&
                  (wx >= 0.0f) && (wx <= (float)(WW - 1));
    if (!inside) return;
    float ty = floorf(wy);
    float lx = floorf(wx);
    int base = b * NN;
#pragma unroll
    for (int k = 0; k < 4; ++k) {
        float ny = ty + (float)(k >> 1);
        float nx = lx + (float)(k & 1);
        int iy = (int)ny;
        int ix = (int)nx;
        if (iy < 0 || iy >= HH || ix < 0 || ix >= WW) continue;
        float wgt_y = fminf(fmaxf(1.0f - fabsf(wy - ny), 0.0f), 1.0f);
        float wgt_x = fminf(fmaxf(1.0f - fabsf(wx - nx), 0.0f), 1.0f);
        float w = wgt_y * wgt_x;
        int fi = base + iy * WW + ix;
        gatomic(&sum_w[fi],  w);
        gatomic(&sum_wy[fi], w * fy);
        gatomic(&sum_wx[fi], w * fx);
    }
}

__global__ void finalize_kernel(const float* __restrict__ sum_w,
                                const float* __restrict__ sum_wy,
                                const float* __restrict__ sum_wx,
                                float* __restrict__ out) {
    int t = blockIdx.x * blockDim.x + threadIdx.x;
    if (t >= BB * NN) return;
    float denom = sum_w[t] + EPS;
    out[t]                   = sum_wx[t] / denom;
    out[(size_t)BB * NN + t] = sum_wy[t] / denom;
}

// ---------------- launch ----------------

extern "C" void kernel_launch(void* const* d_in, const int* in_sizes, int n_in,
                              void* d_out, int out_size, void* d_ws, size_t ws_size,
                              hipStream_t stream) {
    const float* fx_all = (const float*)d_in[0];
    const float* fy_all = (const float*)d_in[1];
    const int* i_ptr    = (const int*)d_in[2];
    const int* tref_ptr = (const int*)d_in[3];
    float* out = (float*)d_out;

    const size_t BN = (size_t)BB * NN;   // 2.4576 M cells
    // ws layout: Sw|Swy|Swx | counter(256B) | list(LCAP*16B)
    const size_t need = 3 * BN * sizeof(float) + 256 + (size_t)LCAP * 16;
    if (ws_size >= need) {
        float* Sw  = (float*)d_ws;
        float* Swy = Sw  + BN;
        float* Swx = Swy + BN;
        unsigned* lcount = (unsigned*)((char*)d_ws + 3 * BN * sizeof(float));
        int4* llist = (int4*)((char*)lcount + 256);

        hipMemsetAsync(lcount, 0, sizeof(unsigned), stream);
        dim3 grid(NBX, NBY, BB);
        bin_gather_splat<<<grid, 256, 0, stream>>>(fx_all, fy_all, i_ptr, tref_ptr,
                                                   Sw, Swy, Swx, lcount, llist, out);
        int fgrid = (int)(LCAP / 256u);
        fix_add<<<fgrid, 256, 0, stream>>>(lcount, llist, Sw, Swy, Swx);
        fix_write<<<fgrid, 256, 0, stream>>>(lcount, llist, Sw, Swy, Swx, out);
    } else {
        // R1 fallback: global-atomic splat (native adds)
        float* sum_w  = (float*)d_ws;
        float* sum_wy = sum_w + BN;
        float* sum_wx = sum_wy + BN;
        hipMemsetAsync(d_ws, 0, 3 * BN * sizeof(float), stream);
        int total = (int)BN;
        int block = 256;
        int grid1 = (total + block - 1) / block;
        splat_kernel<<<grid1, block, 0, stream>>>(fx_all, fy_all, i_ptr, tref_ptr,
                                                  sum_w, sum_wy, sum_wx);
        finalize_kernel<<<grid1, block, 0, stream>>>(sum_w, sum_wy, sum_wx, out);
    }
}

// Round 11
// 95.586 us; speedup vs baseline: 5.0538x; 5.0538x over previous
//
#include <hip/hip_runtime.h>
#include <stdint.h>

// Problem constants (fixed by the reference's config)
#define HH 480
#define WW 640
#define NN (HH * WW)
#define BB 8
#define PP 4
#define EPS 1e-9f

// Output-tile geometry: block owns a TW x TH OUTPUT tile. 640/64=10, 480/32=15.
#define TW 64
#define TH 32
#define HALO 12
#define RGW (TW + 2 * HALO)   // 88
#define RGH (TH + 2 * HALO)   // 56
#define RGN (RGW * RGH)       // 4928
#define NBX (WW / TW)         // 10
#define NBY (HH / TH)         // 15
#define NBLOCKS (NBX * NBY * BB)  // 1200

// Binning: sources bucketed by floor cell.
#define BINSX (TW + 1)        // 65
#define BINSY (TH + 1)        // 33
#define NBINS (BINSX * BINSY) // 2145
#define CAP 4                 // slots/bin; overflow -> list path

// guaranteed-in-image source id (rel HALO,HALO) for dead predicated loads
#define SAFE_ID ((HALO << 7) | HALO)

// per-block far/overflow segment: ~120 entries avg on this input; 1024 = 8+ sigma
#define SEGCAP 1024

__device__ __forceinline__ void gatomic(float* p, float v) {
    unsafeAtomicAdd(p, v);    // native global_atomic_add_f32, rare path only
}

// Phase A: scan halo region, bin sources by floor cell (1 LDS rtn-atomic per
// source); far/overflow contributions appended to THIS BLOCK's list segment
// (LDS counter -- R10's single global counter serialized ~50K rtn-atomics on
// one cacheline and cost ~300 us). Phase B: R9-verbatim consume-immediately
// gather (R10's register-array issue/eval split was demoted to scratch,
// VGPR 44 < live values). Epilogue writes S planes AND normalized out;
// fixup kernels correct the rare list-touched pixels.
__global__ __launch_bounds__(256, 4)
void bin_gather_splat(const float* __restrict__ fx_all,
                      const float* __restrict__ fy_all,
                      const int* __restrict__ i_ptr,
                      const int* __restrict__ tref_ptr,
                      float* __restrict__ Sw, float* __restrict__ Swy, float* __restrict__ Swx,
                      unsigned* __restrict__ segcnt, int4* __restrict__ llist,
                      float* __restrict__ out) {
    __shared__ unsigned cnt[NBINS];   // 8580 B
    __shared__ ushort4  ids4[NBINS];  // 17160 B
    __shared__ unsigned lseg;         // this block's segment counter
    const int tid = threadIdx.x;
    for (int e = tid; e < NBINS; e += 256) cnt[e] = 0;
    if (tid == 0) lseg = 0;
    __syncthreads();

    const int bx = blockIdx.x, by = blockIdx.y, b = blockIdx.z;
    const int bid = (b * NBY + by) * NBX + bx;     // linear block id
    int4* __restrict__ lseg_base = llist + (size_t)bid * SEGCAP;
    const int tx0 = bx * TW, ty0 = by * TH;
    const int i = *i_ptr;
    const float dt = (float)(*tref_ptr - i);
    const float* __restrict__ fxp = fx_all + (size_t)(b * PP + i) * NN;
    const float* __restrict__ fyp = fy_all + (size_t)(b * PP + i) * NN;
    const size_t BN = (size_t)BB * NN;

    // ---------------- phase A ----------------
    for (int sp = tid; sp < RGN; sp += 256) {
        int sy = sp / RGW, sx = sp - sy * RGW;
        int gy = ty0 - HALO + sy, gx = tx0 - HALO + sx;
        if ((unsigned)gy >= (unsigned)HH || (unsigned)gx >= (unsigned)WW) continue;
        int p = gy * WW + gx;
        float fy = fyp[p], fx = fxp[p];
        float wyf = (float)gy + dt * fy;
        float wxf = (float)gx + dt * fx;
        // purge_unfeasible
        if (!(wyf >= 0.0f && wyf <= (float)(HH - 1) &&
              wxf >= 0.0f && wxf <= (float)(WW - 1))) continue;
        float tyf = floorf(wyf), lxf = floorf(wxf);
        int iy0 = (int)tyf, ix0 = (int)lxf;   // >= 0 (inside test)
        int br = iy0 - ty0, bc = ix0 - tx0;

        bool overflow = false;
        if (br >= -1 && br < TH && bc >= -1 && bc < TW) {
            int bin = (br + 1) * BINSX + (bc + 1);
            unsigned slot = atomicAdd(&cnt[bin], 1u);   // native ds_add_rtn_u32
            if (slot < CAP)
                ((unsigned short*)&ids4[bin])[slot] = (unsigned short)((sy << 7) | sx);
            else overflow = true;
        }
        bool interior = ((unsigned)(gx - tx0) < (unsigned)TW) &&
                        ((unsigned)(gy - ty0) < (unsigned)TH);
        if (overflow || interior) {
            float fry = wyf - tyf, frx = wxf - lxf;
            float wts[4] = {(1.0f - fry) * (1.0f - frx),
                            (1.0f - fry) * frx,
                            fry * (1.0f - frx),
                            fry * frx};
#pragma unroll
            for (int k = 0; k < 4; ++k) {
                int iy = iy0 + (k >> 1), ix = ix0 + (k & 1);
                if ((unsigned)iy >= (unsigned)HH || (unsigned)ix >= (unsigned)WW) continue;
                bool inT = ((unsigned)(iy - ty0) < (unsigned)TH) &&
                           ((unsigned)(ix - tx0) < (unsigned)TW);
                // far: s's owner must emit (tile(N) never scans s)
                int tnx = (ix >> 6) << 6;   // tile(N) origin, TW=64
                int tny = (iy >> 5) << 5;   // TH=32
                int ddx = gx < tnx ? tnx - gx : (gx > tnx + (TW - 1) ? gx - tnx - (TW - 1) : 0);
                int ddy = gy < tny ? tny - gy : (gy > tny + (TH - 1) ? gy - tny - (TH - 1) : 0);
                bool far = (ddx > HALO) || (ddy > HALO);
                if ((interior && far) || (overflow && inT)) {
                    int fi = b * NN + iy * WW + ix;
                    float w = wts[k];
                    unsigned slot = atomicAdd(&lseg, 1u);   // LDS rtn-atomic
                    if (slot < SEGCAP)
                        lseg_base[slot] = make_int4(fi, __float_as_int(w),
                                                    __float_as_int(w * fy),
                                                    __float_as_int(w * fx));
                }
            }
        }
    }
    __syncthreads();
    if (tid == 0) segcnt[bid] = lseg > SEGCAP ? SEGCAP : lseg;

    // ---------------- phase B: consume-immediately gather (R9 verbatim) ----------------
    for (int e = tid; e < TW * TH; e += 256) {
        int r = e >> 6, c = e & 63;           // TW=64
        float cy = (float)(ty0 + r), cx = (float)(tx0 + c);
        float ws = 0.f, wys = 0.f, wxs = 0.f;
#pragma unroll
        for (int dr = 0; dr < 2; ++dr) {
#pragma unroll
            for (int dc = 0; dc < 2; ++dc) {
                int bin = (r + dr) * BINSX + (c + dc);
                unsigned n = cnt[bin];
                if (n > CAP) n = CAP;
                ushort4 s4 = ids4[bin];       // one ds_read_b64
                unsigned short sl[4] = {s4.x, s4.y, s4.z, s4.w};
#pragma unroll
                for (int t = 0; t < CAP; ++t) {
                    bool valid = (unsigned)t < n;
                    int id = valid ? (int)sl[t] : SAFE_ID;
                    int sy = id >> 7, sx = id & 127;
                    int gy = ty0 - HALO + sy, gx = tx0 - HALO + sx;
                    int p = gy * WW + gx;     // in-image by construction
                    float fy = fyp[p], fx = fxp[p];   // L1-hot, bit-identical
                    float wyf = (float)gy + dt * fy;  // same expr as phase A
                    float wxf = (float)gx + dt * fx;
                    float ay = 1.0f - fabsf(wyf - cy);
                    float ax = 1.0f - fabsf(wxf - cx);
                    float w = fmaxf(ay, 0.f) * fmaxf(ax, 0.f);
                    w = valid ? w : 0.f;
                    ws  += w;
                    wys += w * fy;
                    wxs += w * fx;
                }
            }
        }
        size_t o = (size_t)b * NN + (size_t)(ty0 + r) * WW + (tx0 + c);
        Sw[o] = ws; Swy[o] = wys; Swx[o] = wxs;
        float d = ws + EPS;
        out[o]      = wxs / d;                // provisional; fixed up if list-touched
        out[BN + o] = wys / d;
    }
}

// ---------------- fixups for list-touched pixels ----------------
__global__ __launch_bounds__(256)
void fix_add(const unsigned* __restrict__ segcnt, const int4* __restrict__ llist,
             float* __restrict__ Sw, float* __restrict__ Swy, float* __restrict__ Swx) {
    unsigned e = blockIdx.x * blockDim.x + threadIdx.x;
    unsigned seg = e / SEGCAP, idx = e - seg * SEGCAP;
    if (seg >= NBLOCKS || idx >= segcnt[seg]) return;
    int4 v = llist[e];
    gatomic(&Sw[v.x],  __int_as_float(v.y));
    gatomic(&Swy[v.x], __int_as_float(v.z));
    gatomic(&Swx[v.x], __int_as_float(v.w));
}

__global__ __launch_bounds__(256)
void fix_write(const unsigned* __restrict__ segcnt, const int4* __restrict__ llist,
               const float* __restrict__ Sw, const float* __restrict__ Swy,
               const float* __restrict__ Swx, float* __restrict__ out) {
    unsigned e = blockIdx.x * blockDim.x + threadIdx.x;
    unsigned seg = e / SEGCAP, idx = e - seg * SEGCAP;
    if (seg >= NBLOCKS || idx >= segcnt[seg]) return;
    int fi = llist[e].x;                      // duplicates benign (idempotent)
    float d = Sw[fi] + EPS;
    out[fi] = Swx[fi] / d;
    out[(size_t)BB * NN + fi] = Swy[fi] / d;
}

// ---------------- fallback path (R1, needs only 29.5 MB ws) ----------------

__global__ void splat_kernel(const float* __restrict__ fx_all,
                             const float* __restrict__ fy_all,
                             const int* __restrict__ i_ptr,
                             const int* __restrict__ tref_ptr,
                             float* __restrict__ sum_w,
                             float* __restrict__ sum_wy,
                             float* __restrict__ sum_wx) {
    int t = blockIdx.x * blockDim.x + threadIdx.x;
    if (t >= BB * NN) return;
    int b = t / NN;
    int p = t - b * NN;
    int i = *i_ptr;
    float dt = (float)(*tref_ptr - i);
    const float fx = fx_all[(size_t)(b * PP + i) * NN + p];
    const float fy = fy_all[(size_t)(b * PP + i) * NN + p];
    float gy = (float)(p / WW);
    float gx = (float)(p - (p / WW) * WW);
    float wy = gy + dt * fy;
    float wx = gx + dt * fx;
    bool inside = (wy >= 0.0f) && (wy <= (float)(HH - 1)) &&
                  (wx >= 0.0f) && (wx <= (float)(WW - 1));
    if (!inside) return;
    float ty = floorf(wy);
    float lx = floorf(wx);
    int base = b * NN;
#pragma unroll
    for (int k = 0; k < 4; ++k) {
        float ny = ty + (float)(k >> 1);
        float nx = lx + (float)(k & 1);
        int iy = (int)ny;
        int ix = (int)nx;
        if (iy < 0 || iy >= HH || ix < 0 || ix >= WW) continue;
        float wgt_y = fminf(fmaxf(1.0f - fabsf(wy - ny), 0.0f), 1.0f);
        float wgt_x = fminf(fmaxf(1.0f - fabsf(wx - nx), 0.0f), 1.0f);
        float w = wgt_y * wgt_x;
        int fi = base + iy * WW + ix;
        gatomic(&sum_w[fi],  w);
        gatomic(&sum_wy[fi], w * fy);
        gatomic(&sum_wx[fi], w * fx);
    }
}

__global__ void finalize_kernel(const float* __restrict__ sum_w,
                                const float* __restrict__ sum_wy,
                                const float* __restrict__ sum_wx,
                                float* __restrict__ out) {
    int t = blockIdx.x * blockDim.x + threadIdx.x;
    if (t >= BB * NN) return;
    float denom = sum_w[t] + EPS;
    out[t]                   = sum_wx[t] / denom;
    out[(size_t)BB * NN + t] = sum_wy[t] / denom;
}

// ---------------- launch ----------------

extern "C" void kernel_launch(void* const* d_in, const int* in_sizes, int n_in,
                              void* d_out, int out_size, void* d_ws, size_t ws_size,
                              hipStream_t stream) {
    const float* fx_all = (const float*)d_in[0];
    const float* fy_all = (const float*)d_in[1];
    const int* i_ptr    = (const int*)d_in[2];
    const int* tref_ptr = (const int*)d_in[3];
    float* out = (float*)d_out;

    const size_t BN = (size_t)BB * NN;   // 2.4576 M cells
    // ws layout: Sw|Swy|Swx | llist (NBLOCKS*SEGCAP*16B) | segcnt (NBLOCKS*4B)
    const size_t s_bytes = 3 * BN * sizeof(float);                 // 29.49 MB (16B-mult)
    const size_t l_bytes = (size_t)NBLOCKS * SEGCAP * sizeof(int4);// 19.66 MB
    const size_t need = s_bytes + l_bytes + NBLOCKS * sizeof(unsigned);
    if (ws_size >= need) {
        float* Sw  = (float*)d_ws;
        float* Swy = Sw  + BN;
        float* Swx = Swy + BN;
        int4* llist = (int4*)((char*)d_ws + s_bytes);
        unsigned* segcnt = (unsigned*)((char*)llist + l_bytes);

        // no memsets: segcnt is written unconditionally by every block,
        // llist beyond segcnt[] is never read, S planes fully overwritten.
        dim3 grid(NBX, NBY, BB);
        bin_gather_splat<<<grid, 256, 0, stream>>>(fx_all, fy_all, i_ptr, tref_ptr,
                                                   Sw, Swy, Swx, segcnt, llist, out);
        int fgrid = (NBLOCKS * SEGCAP) / 256;
        fix_add<<<fgrid, 256, 0, stream>>>(segcnt, llist, Sw, Swy, Swx);
        fix_write<<<fgrid, 256, 0, stream>>>(segcnt, llist, Sw, Swy, Swx, out);
    } else {
        // R1 fallback: global-atomic splat (native adds)
        float* sum_w  = (float*)d_ws;
        float* sum_wy = sum_w + BN;
        float* sum_wx = sum_wy + BN;
        hipMemsetAsync(d_ws, 0, 3 * BN * sizeof(float), stream);
        int total = (int)BN;
        int block = 256;
        int grid1 = (total + block - 1) / block;
        splat_kernel<<<grid1, block, 0, stream>>>(fx_all, fy_all, i_ptr, tref_ptr,
                                                  sum_w, sum_wy, sum_wx);
        finalize_kernel<<<grid1, block, 0, stream>>>(sum_w, sum_wy, sum_wx, out);
    }
}